// Round 1
// baseline (173.928 us; speedup 1.0000x reference)
//
#include <hip/hip_runtime.h>
#include <stdint.h>

// Problem constants (fixed by the reference)
#define BATCH   4096
#define IN_DIM  1024
#define OUT_DIM 1024
#define KDIM    4096   // 4 * IN_DIM

typedef __bf16 bf16x8 __attribute__((ext_vector_type(8)));
typedef float  f32x4  __attribute__((ext_vector_type(4)));

// fp32 -> bf16 bits, round-to-nearest-even
__device__ __forceinline__ uint16_t f2bf(float f) {
    union { float f; uint32_t u; } v; v.f = f;
    uint32_t u = v.u;
    uint32_t r = (u + 0x7FFFu + ((u >> 16) & 1u)) >> 16;
    return (uint16_t)r;
}

// ---------------------------------------------------------------------------
// prep_a: per sample b, compute spline alpha[4] and write
//   A'[b, c*IN + i] = bf16(alpha[c] * x[b,i])   (row-major, K=4096)
// Also stash alpha (fp32, B x 4) for the GEMM epilogue bias term.
// One block per sample; thread t handles 4 consecutive i via float4.
// ---------------------------------------------------------------------------
__global__ __launch_bounds__(256) void prep_a(
    const float* __restrict__ x, const float* __restrict__ phase,
    const float* __restrict__ basis, uint16_t* __restrict__ Ap,
    float* __restrict__ alphaWS)
{
    const int b   = blockIdx.x;
    const int tid = threadIdx.x;
    const float HALF_PI = 1.5707963267948966f;

    float s  = phase[b] / HALF_PI;
    int   q  = (int)floorf(s);
    q = q < 0 ? 0 : (q > 3 ? 3 : q);
    float t  = s - (float)q;
    float t2 = t * t, t3 = t2 * t;

    float coef[4];
#pragma unroll
    for (int j = 0; j < 4; ++j)
        coef[j] = t3 * basis[j] + t2 * basis[4 + j] + t * basis[8 + j] + basis[12 + j];

    // CPI[q][k] = (q+k+3)%4  =>  alpha[c] = coef[(c - q + 1) & 3]
    float alpha[4];
#pragma unroll
    for (int c = 0; c < 4; ++c)
        alpha[c] = coef[(c - q + 1) & 3];

    if (tid < 4) alphaWS[b * 4 + tid] = alpha[tid];

    float4 xv = ((const float4*)(x + (size_t)b * IN_DIM))[tid];
#pragma unroll
    for (int c = 0; c < 4; ++c) {
        ushort4 o;
        o.x = f2bf(alpha[c] * xv.x);
        o.y = f2bf(alpha[c] * xv.y);
        o.z = f2bf(alpha[c] * xv.z);
        o.w = f2bf(alpha[c] * xv.w);
        ((ushort4*)(Ap + (size_t)b * KDIM + c * IN_DIM))[tid] = o;
    }
}

// ---------------------------------------------------------------------------
// prep_b: Bt[o, c*IN + i] = bf16(W[c, o, i]); Bt is (OUT x KDIM) row-major
// (B-transposed GEMM input). One block per (c,o) pair; coalesced both sides.
// ---------------------------------------------------------------------------
__global__ __launch_bounds__(256) void prep_b(
    const float* __restrict__ W, uint16_t* __restrict__ Bt)
{
    const int bid = blockIdx.x;
    const int c   = bid >> 10;
    const int o   = bid & 1023;
    const int tid = threadIdx.x;

    float4 wv = ((const float4*)(W + ((size_t)c << 20) + (size_t)o * IN_DIM))[tid];
    ushort4 ov;
    ov.x = f2bf(wv.x); ov.y = f2bf(wv.y); ov.z = f2bf(wv.z); ov.w = f2bf(wv.w);
    ((ushort4*)(Bt + (size_t)o * KDIM + c * IN_DIM))[tid] = ov;
}

// ---------------------------------------------------------------------------
// GEMM: C[m,n] = sum_k A'[m,k] * Bt[n,k]  + sum_c alpha[m,c]*bias[c,n]
// m97-style: 128x128 block tile, BK=64, 256 threads (4 waves, 2x2 wave grid),
// each wave 64x64 via 4x4 of mfma_f32_16x16x32_bf16.
// Staging: global_load_lds width=16 (wave-uniform LDS base + lane*16).
// ---------------------------------------------------------------------------
__global__ __launch_bounds__(256, 2) void gemm_phase(
    const uint16_t* __restrict__ Ap, const uint16_t* __restrict__ Bt,
    const float* __restrict__ alphaWS, const float* __restrict__ biases,
    float* __restrict__ out)
{
    __shared__ uint16_t As[128 * 64];
    __shared__ uint16_t Bs[128 * 64];

    const int tid  = threadIdx.x;
    const int lane = tid & 63;
    const int wid  = tid >> 6;
    const int wm   = wid >> 1;   // wave row (0..1)
    const int wn   = wid & 1;    // wave col (0..1)
    const int tileM = blockIdx.y * 128;
    const int tileN = blockIdx.x * 128;

    f32x4 acc[4][4];
#pragma unroll
    for (int mi = 0; mi < 4; ++mi)
#pragma unroll
        for (int ni = 0; ni < 4; ++ni)
            acc[mi][ni] = (f32x4){0.f, 0.f, 0.f, 0.f};

    // staging: slice s (=wid*4+j) covers 8 rows; lane l -> row s*8 + l/8,
    // k-chunk (l%8)*8. LDS dest = base(s) + lane*16 bytes, matching row-major
    // [128][64] bf16 exactly (no padding allowed with global_load_lds).
    const int srow = lane >> 3;
    const int scol = (lane & 7) * 8;

    const uint16_t* Ag = Ap + (size_t)tileM * KDIM;
    const uint16_t* Bg = Bt + (size_t)tileN * KDIM;

    for (int kt = 0; kt < KDIM / 64; ++kt) {
        const int k0 = kt * 64;
#pragma unroll
        for (int j = 0; j < 4; ++j) {
            const int s = wid * 4 + j;
            const uint16_t* ga = Ag + (size_t)(s * 8 + srow) * KDIM + k0 + scol;
            __builtin_amdgcn_global_load_lds(
                (const __attribute__((address_space(1))) void*)ga,
                (__attribute__((address_space(3))) void*)(As + s * 512), 16, 0, 0);
            const uint16_t* gb = Bg + (size_t)(s * 8 + srow) * KDIM + k0 + scol;
            __builtin_amdgcn_global_load_lds(
                (const __attribute__((address_space(1))) void*)gb,
                (__attribute__((address_space(3))) void*)(Bs + s * 512), 16, 0, 0);
        }
        __syncthreads();

#pragma unroll
        for (int ks = 0; ks < 2; ++ks) {
            bf16x8 af[4], bfr[4];
#pragma unroll
            for (int mi = 0; mi < 4; ++mi)
                af[mi] = *(const bf16x8*)(As + (wm * 64 + mi * 16 + (lane & 15)) * 64
                                             + ks * 32 + (lane >> 4) * 8);
#pragma unroll
            for (int ni = 0; ni < 4; ++ni)
                bfr[ni] = *(const bf16x8*)(Bs + (wn * 64 + ni * 16 + (lane & 15)) * 64
                                              + ks * 32 + (lane >> 4) * 8);
#pragma unroll
            for (int mi = 0; mi < 4; ++mi)
#pragma unroll
                for (int ni = 0; ni < 4; ++ni)
                    acc[mi][ni] = __builtin_amdgcn_mfma_f32_16x16x32_bf16(
                        af[mi], bfr[ni], acc[mi][ni], 0, 0, 0);
        }
        __syncthreads();
    }

    // Epilogue: out[m,n] = acc + sum_c alpha[m,c]*bias[c,n]
    // C/D layout: col = lane&15, row = (lane>>4)*4 + reg  [m89/m91 verified]
    const int col0 = tileN + wn * 64 + (lane & 15);
    float bvals[4][4];  // [ni][c]
#pragma unroll
    for (int ni = 0; ni < 4; ++ni)
#pragma unroll
        for (int c = 0; c < 4; ++c)
            bvals[ni][c] = biases[c * OUT_DIM + col0 + ni * 16];

#pragma unroll
    for (int mi = 0; mi < 4; ++mi) {
#pragma unroll
        for (int r = 0; r < 4; ++r) {
            const int m = tileM + wm * 64 + mi * 16 + (lane >> 4) * 4 + r;
            f32x4 al = *(const f32x4*)(alphaWS + 4 * m);
#pragma unroll
            for (int ni = 0; ni < 4; ++ni) {
                float be = al[0] * bvals[ni][0] + al[1] * bvals[ni][1]
                         + al[2] * bvals[ni][2] + al[3] * bvals[ni][3];
                out[(size_t)m * OUT_DIM + col0 + ni * 16] = acc[mi][ni][r] + be;
            }
        }
    }
}

extern "C" void kernel_launch(void* const* d_in, const int* in_sizes, int n_in,
                              void* d_out, int out_size, void* d_ws, size_t ws_size,
                              hipStream_t stream)
{
    const float* x       = (const float*)d_in[0];  // (B, IN)
    const float* phase   = (const float*)d_in[1];  // (B,)
    const float* weights = (const float*)d_in[2];  // (4, OUT, IN)
    const float* biases  = (const float*)d_in[3];  // (4, OUT)
    const float* basis   = (const float*)d_in[4];  // (4, 4)
    float* out = (float*)d_out;                    // (B, OUT)

    // Workspace: A' (32 MB bf16) | Bt (8 MB bf16) | alpha (64 KB fp32)
    uint16_t* Ap = (uint16_t*)d_ws;
    uint16_t* Bt = Ap + (size_t)BATCH * KDIM;
    float* alphaWS = (float*)(Bt + (size_t)OUT_DIM * KDIM);

    prep_a<<<BATCH, 256, 0, stream>>>(x, phase, basis, Ap, alphaWS);
    prep_b<<<4096, 256, 0, stream>>>(weights, Bt);

    dim3 grid(OUT_DIM / 128, BATCH / 128);  // 8 x 32 = 256 blocks
    gemm_phase<<<grid, 256, 0, stream>>>(Ap, Bt, alphaWS, biases, out);
}

// Round 2
// 133.806 us; speedup vs baseline: 1.2999x; 1.2999x over previous
//
#include <hip/hip_runtime.h>
#include <stdint.h>

// Problem constants (fixed by the reference)
#define BATCH   4096
#define IN_DIM  1024
#define OUT_DIM 1024

typedef __bf16 bf16x8 __attribute__((ext_vector_type(8)));
typedef float  f32x4  __attribute__((ext_vector_type(4)));

// fp32 -> bf16 bits, round-to-nearest-even
__device__ __forceinline__ uint16_t f2bf(float f) {
    union { float f; uint32_t u; } v; v.f = f;
    uint32_t u = v.u;
    uint32_t r = (u + 0x7FFFu + ((u >> 16) & 1u)) >> 16;
    return (uint16_t)r;
}

// ---------------------------------------------------------------------------
// prep: blocks 0..4095   -> convert x row b to bf16, compute alpha[b][0..3]
//       blocks 4096..8191 -> convert W (flat 4M floats) to bf16
// ---------------------------------------------------------------------------
__global__ __launch_bounds__(256) void prep(
    const float* __restrict__ x, const float* __restrict__ phase,
    const float* __restrict__ basis, const float* __restrict__ W,
    uint16_t* __restrict__ xb, uint16_t* __restrict__ Wb,
    float* __restrict__ alphaWS)
{
    const int bid = blockIdx.x;
    const int tid = threadIdx.x;

    if (bid < BATCH) {
        const int b = bid;
        const float HALF_PI = 1.5707963267948966f;
        float s  = phase[b] / HALF_PI;
        int   q  = (int)floorf(s);
        q = q < 0 ? 0 : (q > 3 ? 3 : q);
        float t  = s - (float)q;
        float t2 = t * t, t3 = t2 * t;

        float coef[4];
#pragma unroll
        for (int j = 0; j < 4; ++j)
            coef[j] = t3 * basis[j] + t2 * basis[4 + j] + t * basis[8 + j] + basis[12 + j];

        // CPI[q][k] = (q+k+3)%4  =>  alpha[c] = coef[(c - q + 1) & 3]
        if (tid < 4) alphaWS[b * 4 + tid] = coef[(tid - q + 1) & 3];

        float4 xv = ((const float4*)(x + (size_t)b * IN_DIM))[tid];
        ushort4 o;
        o.x = f2bf(xv.x); o.y = f2bf(xv.y); o.z = f2bf(xv.z); o.w = f2bf(xv.w);
        ((ushort4*)(xb + (size_t)b * IN_DIM))[tid] = o;
    } else {
        const int j = bid - BATCH;                 // 0..4095, W has 1M float4s
        float4 wv = ((const float4*)W)[j * 256 + tid];
        ushort4 o;
        o.x = f2bf(wv.x); o.y = f2bf(wv.y); o.z = f2bf(wv.z); o.w = f2bf(wv.w);
        ((ushort4*)Wb)[j * 256 + tid] = o;
    }
}

// ---------------------------------------------------------------------------
// gemm_split: P_c[m,n] = sum_k x[m,k] * W[c,n,k]   (K = 1024 per split)
// 128x128 tile, BK=64, 256 threads (2x2 waves, each 64x64 via 4x4 MFMA).
// grid = (32 M-tiles, 8 N-tiles, 4 c) = 1024 blocks -> ~4 blocks/CU.
// M fastest => XCD (round-robin) keeps its A-slice + one B-tile L2-resident.
// LDS XOR swizzle: physical chunk = logical chunk ^ (row & 7), applied on the
// global source address (global_load_lds dest is lane-contiguous, no padding).
// ---------------------------------------------------------------------------
__global__ __launch_bounds__(256, 4) void gemm_split(
    const uint16_t* __restrict__ xb, const uint16_t* __restrict__ Wb,
    float* __restrict__ P0, float* __restrict__ P123)
{
    __shared__ uint16_t As[128 * 64];
    __shared__ uint16_t Bs[128 * 64];

    const int tid  = threadIdx.x;
    const int lane = tid & 63;
    const int wid  = tid >> 6;
    const int wm   = wid >> 1;
    const int wn   = wid & 1;
    const int tileM = blockIdx.x * 128;
    const int tileN = blockIdx.y * 128;
    const int c     = blockIdx.z;

    f32x4 acc[4][4];
#pragma unroll
    for (int mi = 0; mi < 4; ++mi)
#pragma unroll
        for (int ni = 0; ni < 4; ++ni)
            acc[mi][ni] = (f32x4){0.f, 0.f, 0.f, 0.f};

    // staging: slice s (=wid*4+j) covers rows 8s..8s+7; lane l -> row l>>3,
    // physical chunk l&7; source global chunk = (l&7) ^ (l>>3)  (XOR swizzle)
    const int srow = lane >> 3;
    const int gchunk = ((lane & 7) ^ srow) * 8;   // element offset of 8-elem chunk

    const uint16_t* Ag = xb + (size_t)tileM * 1024;
    const uint16_t* Bg = Wb + ((size_t)c << 20) + (size_t)tileN * 1024;

    const int quad = lane >> 4;
    const int l7   = lane & 7;

    for (int kt = 0; kt < 16; ++kt) {
        const int k0 = kt * 64;
#pragma unroll
        for (int j = 0; j < 4; ++j) {
            const int s = wid * 4 + j;
            const uint16_t* ga = Ag + (size_t)(s * 8 + srow) * 1024 + k0 + gchunk;
            __builtin_amdgcn_global_load_lds(
                (const __attribute__((address_space(1))) void*)ga,
                (__attribute__((address_space(3))) void*)(As + s * 512), 16, 0, 0);
            const uint16_t* gb = Bg + (size_t)(s * 8 + srow) * 1024 + k0 + gchunk;
            __builtin_amdgcn_global_load_lds(
                (const __attribute__((address_space(1))) void*)gb,
                (__attribute__((address_space(3))) void*)(Bs + s * 512), 16, 0, 0);
        }
        __syncthreads();

#pragma unroll
        for (int ks = 0; ks < 2; ++ks) {
            bf16x8 af[4], bfr[4];
#pragma unroll
            for (int mi = 0; mi < 4; ++mi) {
                const int row = wm * 64 + mi * 16 + (lane & 15);
                const int ch  = (ks * 4 + quad) ^ l7;     // physical chunk
                af[mi] = *(const bf16x8*)(As + row * 64 + ch * 8);
            }
#pragma unroll
            for (int ni = 0; ni < 4; ++ni) {
                const int row = wn * 64 + ni * 16 + (lane & 15);
                const int ch  = (ks * 4 + quad) ^ l7;
                bfr[ni] = *(const bf16x8*)(Bs + row * 64 + ch * 8);
            }
#pragma unroll
            for (int mi = 0; mi < 4; ++mi)
#pragma unroll
                for (int ni = 0; ni < 4; ++ni)
                    acc[mi][ni] = __builtin_amdgcn_mfma_f32_16x16x32_bf16(
                        af[mi], bfr[ni], acc[mi][ni], 0, 0, 0);
        }
        __syncthreads();
    }

    // partial store (no alpha/bias here; fp32)
    float* Pc = (c == 0) ? P0 : (P123 + (size_t)(c - 1) * (BATCH * (size_t)OUT_DIM));
    const int col0 = tileN + wn * 64 + (lane & 15);
#pragma unroll
    for (int mi = 0; mi < 4; ++mi) {
#pragma unroll
        for (int r = 0; r < 4; ++r) {
            const int m = tileM + wm * 64 + mi * 16 + quad * 4 + r;
#pragma unroll
            for (int ni = 0; ni < 4; ++ni)
                Pc[(size_t)m * OUT_DIM + col0 + ni * 16] = acc[mi][ni][r];
        }
    }
}

// ---------------------------------------------------------------------------
// reduce: out[m,n] = sum_c alpha[m,c] * (P_c[m,n] + bias[c,n])
// P_0 aliases d_out; each thread reads its own element before writing it.
// ---------------------------------------------------------------------------
__global__ __launch_bounds__(256) void reduce_k(
    const float* __restrict__ P123, const float* __restrict__ alphaWS,
    const float* __restrict__ biases, float* __restrict__ out)
{
    const int m = blockIdx.x;
    const int t = threadIdx.x;
    const size_t stride = (size_t)BATCH * OUT_DIM;

    const float4 al = *(const float4*)(alphaWS + 4 * m);
    const float4 p0 = ((const float4*)(out + (size_t)m * OUT_DIM))[t];
    const float4 p1 = ((const float4*)(P123 + 0 * stride + (size_t)m * OUT_DIM))[t];
    const float4 p2 = ((const float4*)(P123 + 1 * stride + (size_t)m * OUT_DIM))[t];
    const float4 p3 = ((const float4*)(P123 + 2 * stride + (size_t)m * OUT_DIM))[t];
    const float4 b0 = ((const float4*)(biases + 0 * OUT_DIM))[t];
    const float4 b1 = ((const float4*)(biases + 1 * OUT_DIM))[t];
    const float4 b2 = ((const float4*)(biases + 2 * OUT_DIM))[t];
    const float4 b3 = ((const float4*)(biases + 3 * OUT_DIM))[t];

    float4 r;
    r.x = al.x * (p0.x + b0.x) + al.y * (p1.x + b1.x) + al.z * (p2.x + b2.x) + al.w * (p3.x + b3.x);
    r.y = al.x * (p0.y + b0.y) + al.y * (p1.y + b1.y) + al.z * (p2.y + b2.y) + al.w * (p3.y + b3.y);
    r.z = al.x * (p0.z + b0.z) + al.y * (p1.z + b1.z) + al.z * (p2.z + b2.z) + al.w * (p3.z + b3.z);
    r.w = al.x * (p0.w + b0.w) + al.y * (p1.w + b1.w) + al.z * (p2.w + b2.w) + al.w * (p3.w + b3.w);
    ((float4*)(out + (size_t)m * OUT_DIM))[t] = r;
}

extern "C" void kernel_launch(void* const* d_in, const int* in_sizes, int n_in,
                              void* d_out, int out_size, void* d_ws, size_t ws_size,
                              hipStream_t stream)
{
    const float* x       = (const float*)d_in[0];  // (B, IN)
    const float* phase   = (const float*)d_in[1];  // (B,)
    const float* weights = (const float*)d_in[2];  // (4, OUT, IN)
    const float* biases  = (const float*)d_in[3];  // (4, OUT)
    const float* basis   = (const float*)d_in[4];  // (4, 4)
    float* out = (float*)d_out;                    // (B, OUT)

    // Workspace: xb bf16 8 MB | Wb bf16 8 MB | alpha 64 KB | P_{1,2,3} fp32 48 MB
    // (P_0 lives in d_out). Total ~64.1 MB.
    uint16_t* xb = (uint16_t*)d_ws;
    uint16_t* Wb = xb + (size_t)BATCH * IN_DIM;
    float* alphaWS = (float*)(Wb + (size_t)4 * OUT_DIM * IN_DIM);
    float* P123 = alphaWS + (size_t)BATCH * 4;

    prep<<<2 * BATCH, 256, 0, stream>>>(x, phase, basis, weights, xb, Wb, alphaWS);

    dim3 grid(BATCH / 128, OUT_DIM / 128, 4);  // M fastest for XCD L2 locality
    gemm_split<<<grid, 256, 0, stream>>>(xb, Wb, out, P123);

    reduce_k<<<BATCH, 256, 0, stream>>>(P123, alphaWS, biases, out);
}